// Round 9
// baseline (171.346 us; speedup 1.0000x reference)
//
#include <hip/hip_runtime.h>

#define HIMG 256
#define WIMG 256
#define CCH  32
#define JBOX 64
#define BIMG 8
#define HGT  8
#define NBUF 3
#define WCOLS 52   // 52 lanes x 16B = 832B window: cols xs4 .. xs4+207
#define OSW  208   // out-stage row width (floats); max_w <= 199 proven from box bounds

// R19: cut OUTPUT STORE INSTRUCTIONS 4x. The last invariant across all six
// 54us variants (R10,R11,R12,R13,R14,R18) is the store stream: ~345K
// global_store_dword instrs (86MB / 256B-per-wave-store). The harness's own
// fillBufferAligned writes exactly 4x our bytes in the SAME 54.2us with
// 1KB-per-instr stores -- both kernels sit at ~6.3K store-instrs/us
// device-wide. Theory: store-instruction rate is the binder; payload per
// instruction is the lever.
// - consume results go to a wave-private LDS out-stage (stride-1 ds_write2,
//   conflict-free) instead of registers;
// - epilogue re-reads the out-stage FLAT and stores the job's contiguous
//   8*max_w-float region with global_store_dwordx4: the region is provably
//   16B-aligned with 16B-multiple length (32*max_w % 16 == 0) -> ~6 dwordx4
//   stores per job, zero tails. 337K -> ~108K store instrs device-wide.
// Everything else is R18 verbatim: channel-outer grid, wave=(bj,c), 3-deep
// global_load_lds pipeline, counted vmcnt(4/4/4/4/4/4/2/0) with a DMA-only
// vmcnt domain, zero barriers. Numerics: tap/rounding/blend expressions
// byte-identical to R11-R18 (all passed absmax).
typedef __attribute__((address_space(3))) float lds_f;
typedef const __attribute__((address_space(1))) float glb_f;

__global__ __launch_bounds__(256, 3) void roi_kernel(
    const float* __restrict__ img,     // (B, C, HIMG, WIMG)
    const float* __restrict__ boxes,   // (B, J, 5)
    float* __restrict__ res,           // (B, J, C, HGT, max_w)
    float* __restrict__ mask,          // (B, J, max_w)
    int max_w)
{
    __shared__ float sbuf[4][NBUF][2][208];   // in-stage: 19,968 B
    __shared__ float ostage[4][HGT][OSW];     // out-stage: 26,624 B (46.6KB tot)

    const int d    = blockIdx.x;
    const int b    = d & 7;                // XCD-pinned image
    const int seq  = d >> 3;               // 0..511
    const int cg   = seq >> 6;             // 0..7  CHANNEL-OUTER (R18: FETCH 29MB)
    const int j    = seq & 63;             // box-inner
    const int bj   = b * JBOX + j;
    const int tid  = threadIdx.x;
    const int wv   = tid >> 6;             // wave 0..3 (uniform)
    const int lane = tid & 63;
    const int c    = cg * 4 + wv;          // channel 0..31 (wave-uniform)

    const float left = boxes[bj * 5 + 0];
    const float top  = boxes[bj * 5 + 1];
    const float bw   = boxes[bj * 5 + 2] - left;
    const float bh   = boxes[bj * 5 + 3] - top;

    // width = int32(bw/bh * 8) with f32 ops + truncation (matches numpy).
    const int   width  = (int)(bw / bh * 8.0f);
    const float each_w = bw / ((float)width - 1.0f);
    const float each_h = bh / 7.0f;

    const int xs  = max((int)floorf(left), 0);   // <= 40
    const int xs4 = xs & ~3;                     // 16B-aligned window start

    // ---- per-lane x taps for active column chunks (h-invariant) ----
    int   lxk[4];
    float wx0k[4], wx1k[4];
    #pragma unroll
    for (int k = 0; k < 4; ++k) {
        if (64 * k < max_w) {              // wave-uniform guard
            const int   i  = 64 * k + lane;
            const float x  = __fadd_rn(__fmul_rn((float)i, each_w), left);
            const int   xf = (int)floorf(x);
            const int   x0 = min(max(xf, 0), WIMG - 1);
            wx1k[k] = (float)(x0 + 1) - x;
            wx0k[k] = x - (float)x0;
            lxk[k]  = min(max(x0 - xs4, 0), 206);   // window pos, +1 <= 207
        }
    }

    const float* chbase = img + (size_t)(b * CCH + c) * (HIMG * WIMG);

    // DMA the two y-rows (832B window each) for step h into buffer bf.
    auto dma = [&](int h, int bf) {
        const float yh  = __fadd_rn(__fmul_rn((float)h, each_h), top);
        const int   yfl = (int)floorf(yh);
        const int   ya  = min(max(yfl,     0), HIMG - 1);
        const int   yb  = min(max(yfl + 1, 0), HIMG - 1);
        if (lane < WCOLS) {                // always >=1 lane -> instr always issued
            const float* s0 = chbase + (size_t)ya * WIMG + xs4 + 4 * lane;
            const float* s1 = chbase + (size_t)yb * WIMG + xs4 + 4 * lane;
            __builtin_amdgcn_global_load_lds((glb_f*)s0, (lds_f*)&sbuf[wv][bf][0][0], 16, 0, 0);
            __builtin_amdgcn_global_load_lds((glb_f*)s1, (lds_f*)&sbuf[wv][bf][1][0], 16, 0, 0);
        }
    };

    // Consume step h from buffer bf; results -> wave-private LDS out-stage.
    auto consume = [&](int h, int bf) {
        const float yh  = __fadd_rn(__fmul_rn((float)h, each_h), top);
        const int   yfl = (int)floorf(yh);
        const int   ya  = min(max(yfl,     0), HIMG - 1);
        const int   yb  = min(max(yfl + 1, 0), HIMG - 1);
        const float wy1 = (float)yb - yh;
        const float wy0 = yh - (float)ya;
        #pragma unroll
        for (int k = 0; k < 4; ++k) {
            if (64 * k < max_w) {          // wave-uniform guard
                const int   ii  = 64 * k + lane;
                const float v00 = sbuf[wv][bf][0][lxk[k]];      // ds_read2_b32
                const float v01 = sbuf[wv][bf][0][lxk[k] + 1];
                const float v10 = sbuf[wv][bf][1][lxk[k]];      // ds_read2_b32
                const float v11 = sbuf[wv][bf][1][lxk[k] + 1];
                const float wa  = wx1k[k] * wy1;
                const float wb_ = wx1k[k] * wy0;
                const float wc_ = wx0k[k] * wy1;
                const float wd_ = wx0k[k] * wy0;
                // identical term order/grouping to R11-R18 (passed absmax):
                const float val = v00 * wa + v10 * wb_ + v01 * wc_ + v11 * wd_;
                // stride-1 across lanes: conflict-free ds_write (write2-merged)
                ostage[wv][h][ii] = (ii < width) ? val : 0.0f;
            }
        }
    };

    // prologue: 3 steps in flight (6 DMA ops; vmcnt domain = DMA ONLY:
    // no global stores exist anywhere before the epilogue)
    dma(0, 0);
    dma(1, 1);
    dma(2, 2);
    __builtin_amdgcn_sched_barrier(0);

#define STEP(H, BF, WN)                                                       \
    do {                                                                      \
        asm volatile("s_waitcnt vmcnt(" #WN ")" ::: "memory");                \
        __builtin_amdgcn_sched_barrier(0);                                    \
        consume(H, BF);                                                       \
        /* own ds_reads retired before DMA may overwrite this buffer */       \
        asm volatile("s_waitcnt lgkmcnt(0)" ::: "memory");                    \
        __builtin_amdgcn_sched_barrier(0);                                    \
        if ((H) + 3 < HGT) dma((H) + 3, BF);                                  \
    } while (0)

    STEP(0, 0, 4);   // out {0,1,2}: leave 4 => pair(0) done
    STEP(1, 1, 4);
    STEP(2, 2, 4);
    STEP(3, 0, 4);
    STEP(4, 1, 4);
    STEP(5, 2, 4);
    STEP(6, 0, 2);   // out {6,7}: leave 2 => pair(6) done
    STEP(7, 1, 0);   // drain (also fences all out-stage ds_writes via lgkm)
#undef STEP

    // ---- epilogue: flat dwordx4 stores of the contiguous job region ----
    // region = res + (bj*32+c)*8*max_w floats: 16B-aligned (32*max_w%16==0),
    // length 8*max_w floats = multiple of 16B -> zero tails.
    float* jobbase = res + (size_t)(bj * CCH + c) * (size_t)(HGT * max_w);
    const int m  = max_w;
    const int m2 = 2 * m, m4 = 4 * m;
    for (int g = lane; g < 2 * m; g += 64) {   // dwordx4 group index
        int p = 4 * g;                         // flat dword position
        int h = 0;
        if (p >= m4) { h  = 4; p -= m4; }
        if (p >= m2) { h += 2; p -= m2; }
        if (p >= m)  { h += 1; p -= m; }       // p = i within row h, h<=7
        // 4 dwords p..p+3 may cross one row boundary (never past h=7):
        const int c1 = (p + 1 >= m), c2 = (p + 2 >= m), c3 = (p + 3 >= m);
        float4 v;
        v.x = ostage[wv][h][p];
        v.y = ostage[wv][h + c1][p + 1 - (c1 ? m : 0)];
        v.z = ostage[wv][h + c2][p + 2 - (c2 ? m : 0)];
        v.w = ostage[wv][h + c3][p + 3 - (c3 ? m : 0)];
        *reinterpret_cast<float4*>(jobbase + (size_t)4 * g) = v;  // 16B-aligned
    }

    if (cg == 0 && wv == 0) {                  // mask: tiny, keep dword stores
        #pragma unroll
        for (int k = 0; k < 4; ++k) {
            const int ii = 64 * k + lane;
            if (ii < max_w)
                mask[(size_t)bj * max_w + ii] = (ii < width) ? 1.0f : 0.0f;
        }
    }
}

extern "C" void kernel_launch(void* const* d_in, const int* in_sizes, int n_in,
                              void* d_out, int out_size, void* d_ws, size_t ws_size,
                              hipStream_t stream) {
    const float* img   = (const float*)d_in[0];
    const float* boxes = (const float*)d_in[1];
    float* out = (float*)d_out;

    const int per_w = BIMG * JBOX * CCH * HGT + BIMG * JBOX;  // 131584
    const int max_w = out_size / per_w;

    float* res  = out;
    float* mask = out + (size_t)BIMG * JBOX * CCH * HGT * max_w;

    const int blocks = BIMG * JBOX * CCH / 4;   // 4096 = (cg, j) per XCD-image
    roi_kernel<<<blocks, 256, 0, stream>>>(img, boxes, res, mask, max_w);
}